// Round 8
// baseline (120.980 us; speedup 1.0000x reference)
//
#include <hip/hip_runtime.h>

#define NF 40
#define NE 128
#define NA 128
#define NP 780        // NF*(NF-1)/2
#define NPT 784       // padded to 49*16
#define NMT 49        // m-tiles of 16 pairs per sample
#define NT2 98        // m-tiles for 2 samples
#define XS_LD 132     // fp32 x LDS row stride (floats): 16B aligned, spreads banks
#define G_LD 44       // G row stride (floats): multiple of 4 -> 16B-aligned float4 rows

typedef short short8 __attribute__((ext_vector_type(8)));
typedef float floatx4 __attribute__((ext_vector_type(4)));

__device__ __forceinline__ unsigned cvt_pk_bf16(float lo, float hi) {
    // D[15:0] = bf16(S0), D[31:16] = bf16(S1), RNE
    unsigned r;
    asm("v_cvt_pk_bf16_f32 %0, %1, %2" : "=v"(r) : "v"(lo), "v"(hi));
    return r;
}

// sum across each 16-lane row via DPP row_ror (VALU pipe, no DS traffic)
__device__ __forceinline__ float rowsum16(float x) {
    x += __int_as_float(__builtin_amdgcn_update_dpp(0, __float_as_int(x), 0x121, 0xf, 0xf, true)); // ror:1
    x += __int_as_float(__builtin_amdgcn_update_dpp(0, __float_as_int(x), 0x122, 0xf, 0xf, true)); // ror:2
    x += __int_as_float(__builtin_amdgcn_update_dpp(0, __float_as_int(x), 0x124, 0xf, 0xf, true)); // ror:4
    x += __int_as_float(__builtin_amdgcn_update_dpp(0, __float_as_int(x), 0x128, 0xf, 0xf, true)); // ror:8
    return x;
}

// ---- prep: W fp32 -> bf16 into workspace; pair-index table into workspace ----
__global__ __launch_bounds__(256)
void afm_prep_kernel(const float* __restrict__ wg,
                     unsigned short* __restrict__ wbf,
                     int* __restrict__ ijg)
{
    const int t = blockIdx.x * 256 + threadIdx.x;   // 4096 threads
    if (t < NA * NE / 4) {
        float4 v = *(const float4*)(wg + t * 4);
        uint2 pk;
        pk.x = cvt_pk_bf16(v.x, v.y);
        pk.y = cvt_pk_bf16(v.z, v.w);
        *(uint2*)(wbf + t * 4) = pk;
    }
    if (t < NPT) {
        int v = 0;
        if (t < NP) {
            int i = 0, rem = t;
            while (rem >= (NF - 1 - i)) { rem -= (NF - 1 - i); ++i; }
            v = (i << 8) | (i + 1 + rem);
        }
        ijg[t] = v;
    }
}

__global__ __launch_bounds__(256, 2)
void afm_fused_kernel(const float* __restrict__ xg,          // [B, F, E]
                      const unsigned short* __restrict__ wbf,// [A, E] bf16 (prepped)
                      const int* __restrict__ ijg,           // [NPT] packed (i<<8)|j
                      const float* __restrict__ wbg,         // [A]
                      const float* __restrict__ hg,          // [1, A]
                      const float* __restrict__ pwg,         // [1, E]
                      const float* __restrict__ pbg,         // [1]
                      float* __restrict__ out)               // [B]
{
    __shared__ float xs[2][NF][XS_LD];       // 42240 B fp32 x, 2 samples
    __shared__ float sc[2][NPT];             // 6272 B scores
    __shared__ int   ij[NPT];                // 3136 B packed (i<<8)|j (0 for p>=NP)
    __shared__ float G[2][NF][G_LD];         // 14080 B symmetric exp-weight matrices
    __shared__ float afmp[2][2][NE];         // 4096 B afm partials (2 waves per sample)
    __shared__ float red_max4[2][4], red_sum[2][2], red_out[2][2];

    const int tid  = threadIdx.x;
    const int b    = blockIdx.x;             // handles samples 2b, 2b+1
    const int lane = tid & 63;
    const int wid  = tid >> 6;
    const int col  = lane & 15;
    const int quad = (lane >> 4) & 3;

    // ---- stage x for both samples (fp32) ----
    const float* xb = xg + (size_t)b * (2 * NF * NE);
    for (int t = tid; t < 2 * NF * (NE / 4); t += 256) {   // 2560 -> 10 iters
        int s   = (t >= 1280) ? 1 : 0;
        int rem = t - s * 1280;
        int row = rem >> 5, c = (rem & 31) * 4;
        float4 v = *(const float4*)(xb + s * (NF * NE) + row * NE + c);
        *(float4*)&xs[s][row][c] = v;
    }
    // ---- pair index table: copy from prepped global ----
    if (tid < NPT / 4) {
        *(int4*)&ij[tid * 4] = ((const int4*)ijg)[tid];
    }
    // ---- G diagonals zero (exp phase never writes them) ----
    if (tid < 2 * NF) {
        int s = tid / NF, f = tid - s * NF;
        G[s][f][f] = 0.f;
    }
    // ---- per-lane epilogue constants (indexed by col) ----
    float wbr[8], hr[8];
#pragma unroll
    for (int n = 0; n < 8; ++n) {
        wbr[n] = wbg[n * 16 + col];
        hr[n]  = hg[n * 16 + col];
    }
    // ---- W B-fragments into registers (one-time, shared across both samples) ----
    short8 bfrag[8][4];
#pragma unroll
    for (int n = 0; n < 8; ++n)
#pragma unroll
        for (int k = 0; k < 4; ++k)
            bfrag[n][k] = *(const short8*)(wbf + (n * 16 + col) * NE + k * 32 + quad * 8);
    __syncthreads();

    // ---- main MFMA loop over 98 tiles (2 samples); running max tracked in regs ----
    float mloc0 = -1e30f, mloc1 = -1e30f;
    for (int g = wid; g < NT2; g += 4) {
        const int s  = (g >= NMT) ? 1 : 0;
        const int mt = g - s * NMT;
        const int p0 = mt * 16;
        const int v  = ij[p0 + col];
        const float* xip = &xs[s][(v >> 8) & 255][0];
        const float* xjp = &xs[s][v & 255][0];

        floatx4 acc[8];
#pragma unroll
        for (int n = 0; n < 8; ++n)
            acc[n] = (floatx4){wbr[n], wbr[n], wbr[n], wbr[n]};  // bias folded into C-init

#pragma unroll
        for (int k = 0; k < 4; ++k) {
            const int koff = k * 32 + quad * 8;
            float4 i0 = *(const float4*)(xip + koff);
            float4 i1 = *(const float4*)(xip + koff + 4);
            float4 j0 = *(const float4*)(xjp + koff);
            float4 j1 = *(const float4*)(xjp + koff + 4);
            union { short8 s8; unsigned u[4]; } af;
            af.u[0] = cvt_pk_bf16(i0.x * j0.x, i0.y * j0.y);
            af.u[1] = cvt_pk_bf16(i0.z * j0.z, i0.w * j0.w);
            af.u[2] = cvt_pk_bf16(i1.x * j1.x, i1.y * j1.y);
            af.u[3] = cvt_pk_bf16(i1.z * j1.z, i1.w * j1.w);
#pragma unroll
            for (int n = 0; n < 8; ++n)
                acc[n] = __builtin_amdgcn_mfma_f32_16x16x32_bf16(af.s8, bfrag[n][k], acc[n], 0, 0, 0);
        }

        // scores[p] = sum_a relu(S[p,a]) * h[a]   (h_b cancels in softmax)
        float ps[4] = {0.f, 0.f, 0.f, 0.f};
#pragma unroll
        for (int n = 0; n < 8; ++n) {
#pragma unroll
            for (int r = 0; r < 4; ++r)
                ps[r] += fmaxf(acc[n][r], 0.f) * hr[n];
        }
#pragma unroll
        for (int r = 0; r < 4; ++r) ps[r] = rowsum16(ps[r]);

        float pm = -1e30f;
#pragma unroll
        for (int r = 0; r < 4; ++r)
            pm = fmaxf(pm, (p0 + quad * 4 + r < NP) ? ps[r] : -1e30f);
        if (s) mloc1 = fmaxf(mloc1, pm); else mloc0 = fmaxf(mloc0, pm);

        if (col == 0) {
#pragma unroll
            for (int r = 0; r < 4; ++r) {
                int p = p0 + quad * 4 + r;
                if (p < NP) sc[s][p] = ps[r];
            }
        }
    }
    // publish per-wave per-sample maxes (no LDS rescan phase needed)
#pragma unroll
    for (int off = 1; off < 64; off <<= 1) {
        mloc0 = fmaxf(mloc0, __shfl_xor(mloc0, off));
        mloc1 = fmaxf(mloc1, __shfl_xor(mloc1, off));
    }
    if (lane == 0) { red_max4[0][wid] = mloc0; red_max4[1][wid] = mloc1; }
    __syncthreads();

    // ---- per-sample phases: wave pair (s = wid>>1) handles sample s ----
    const int s    = wid >> 1;
    const int lw   = wid & 1;
    const int ltid = (lw << 6) | lane;      // 0..127 within the sample's wave pair
    const float M = fmaxf(fmaxf(red_max4[s][0], red_max4[s][1]),
                          fmaxf(red_max4[s][2], red_max4[s][3]));

    // exp + sum + G-build fused (G holds exp weights; sc dead after)
    float sum = 0.f;
    for (int p = ltid; p < NP; p += 128) {
        int v = ij[p];
        float e = __expf(sc[s][p] - M);
        G[s][(v >> 8) & 255][v & 255] = e;
        G[s][v & 255][(v >> 8) & 255] = e;
        sum += e;
    }
#pragma unroll
    for (int off = 1; off < 64; off <<= 1) sum += __shfl_xor(sum, off);
    if (lane == 0) red_sum[s][lw] = sum;
    __syncthreads();

    // ---- afm[e] = 0.5 * sum_i x[i,e] * (G x)[i,e]  (fp32); 2 waves x 20 rows ----
    {
        const int e2 = lane * 2;
        float2 xc[NF];
#pragma unroll
        for (int j = 0; j < NF; ++j) xc[j] = *(const float2*)&xs[s][j][e2];

        float a0 = 0.f, a1 = 0.f;
#pragma unroll
        for (int ii = 0; ii < 20; ++ii) {
            const int i = lw * 20 + ii;
            float y0 = 0.f, y1 = 0.f;
#pragma unroll
            for (int jj = 0; jj < 10; ++jj) {
                float4 g = *(const float4*)&G[s][i][jj * 4];   // wave-uniform broadcast
                y0 += g.x * xc[jj * 4 + 0].x;  y1 += g.x * xc[jj * 4 + 0].y;
                y0 += g.y * xc[jj * 4 + 1].x;  y1 += g.y * xc[jj * 4 + 1].y;
                y0 += g.z * xc[jj * 4 + 2].x;  y1 += g.z * xc[jj * 4 + 2].y;
                y0 += g.w * xc[jj * 4 + 3].x;  y1 += g.w * xc[jj * 4 + 3].y;
            }
            float2 xi = *(const float2*)&xs[s][i][e2];         // keeps xc[] statically indexed
            a0 += xi.x * y0;
            a1 += xi.y * y1;
        }
        *(float2*)&afmp[s][lw][e2] = make_float2(a0 * 0.5f, a1 * 0.5f);
    }
    __syncthreads();

    // ---- out[2b+s] = (sum_e afm_un[e] * pw[e]) / sum_exp + p_b ----
    {
        float a  = afmp[s][0][ltid] + afmp[s][1][ltid];   // ltid covers e = 0..127
        float vv = a * pwg[ltid];
#pragma unroll
        for (int off = 1; off < 64; off <<= 1) vv += __shfl_xor(vv, off);
        if (lane == 0) red_out[s][lw] = vv;
    }
    __syncthreads();
    if ((tid & 127) == 0) {                  // tid 0 -> s=0, tid 128 -> s=1
        float S   = red_sum[s][0] + red_sum[s][1];
        float tot = red_out[s][0] + red_out[s][1];
        out[2 * b + s] = tot / S + pbg[0];
    }
}

extern "C" void kernel_launch(void* const* d_in, const int* in_sizes, int n_in,
                              void* d_out, int out_size, void* d_ws, size_t ws_size,
                              hipStream_t stream) {
    const float* xg  = (const float*)d_in[0];  // x [B,F,E]
    const float* wg  = (const float*)d_in[1];  // attn_w_w [A,E]
    const float* wbg = (const float*)d_in[2];  // attn_w_b [A]
    const float* hg  = (const float*)d_in[3];  // attn_h_w [1,A]
    // d_in[4] = attn_h_b : constant shift, cancels in softmax
    const float* pwg = (const float*)d_in[5];  // attn_p_w [1,E]
    const float* pbg = (const float*)d_in[6];  // attn_p_b [1]
    const int B = in_sizes[0] / (NF * NE);

    unsigned short* wbf = (unsigned short*)d_ws;                        // 32768 B (bf16 W)
    int* ijg = (int*)((char*)d_ws + NA * NE * sizeof(unsigned short));  // 3136 B

    afm_prep_kernel<<<16, 256, 0, stream>>>(wg, wbf, ijg);
    afm_fused_kernel<<<B / 2, 256, 0, stream>>>(xg, wbf, ijg, wbg, hg, pwg, pbg, (float*)d_out);
}